// Round 23
// baseline (139.524 us; speedup 1.0000x reference)
//
#include <hip/hip_runtime.h>
#include <hip/hip_bf16.h>

typedef __attribute__((ext_vector_type(8))) short short8;   // 8 bf16 (4 VGPRs)
typedef __attribute__((ext_vector_type(4))) float f32x4;
typedef unsigned short u16;
typedef unsigned int u32;

#define SEQ 4096

__device__ __forceinline__ u16 f2bf(float f) {
  return __builtin_bit_cast(u16, __float2bfloat16(f));
}

// exp2: builtin (compiler handles TRANS hazards) or libm fallback. NO raw asm.
#if __has_builtin(__builtin_amdgcn_exp2f)
#define EXP2(x) __builtin_amdgcn_exp2f(x)
#else
#define EXP2(x) exp2f(x)
#endif

// pack two f32 -> bf16x2 (round-half-up via +0x8000, then byte-perm the hi16s)
__device__ __forceinline__ u32 pk2(float a, float b) {
  u32 ua = __builtin_bit_cast(u32, a) + 0x8000u;
  u32 ub = __builtin_bit_cast(u32, b) + 0x8000u;
  return __builtin_amdgcn_perm(ub, ua, 0x07060302);  // {hi16(ub), hi16(ua)}
}

// pack two f32 -> bf16x2 TRUNCATING (1 op). Safe for P: the ones-MFMA row-sum
// is computed from the SAME truncated values, so the softmax ratio is unbiased.
__device__ __forceinline__ u32 pk2t(float a, float b) {
  return __builtin_amdgcn_perm(__builtin_bit_cast(u32, b),
                               __builtin_bit_cast(u32, a), 0x07060302);
}

// global -> LDS direct (16B/lane). LDS dest = wave-uniform base + lane*16.
typedef __attribute__((address_space(1))) u32 gas_u32;
typedef __attribute__((address_space(3))) u32 las_u32;
__device__ __forceinline__ void gload16(const u16* g, const u16* l) {
  __builtin_amdgcn_global_load_lds((gas_u32*)(unsigned long long)(const void*)g,
                                   (las_u32*)(u32)(unsigned long long)(const void*)l,
                                   16, 0, 0);
}

// explicit own-wave vmem drain (belt for the barrier's implicit drain)
#define VM_DRAIN() asm volatile("s_waitcnt vmcnt(0)" ::: "memory")

// ---------------- fused prep (ONE launch): x->bf16, RoPE tables, W transposes -----
__global__ __launch_bounds__(256) void k_prep(const float* __restrict__ x,
                                              u16* __restrict__ xb,
                                              float* __restrict__ cosT,
                                              float* __restrict__ sinT,
                                              const float* __restrict__ Wq,
                                              const float* __restrict__ Wk,
                                              const float* __restrict__ Wv,
                                              const float* __restrict__ Wo,
                                              u16* __restrict__ Wt,
                                              u16* __restrict__ Wto) {
  int bid = blockIdx.x;
  if (bid < 4096) {
    int i = bid * 256 + threadIdx.x;     // one float4 each
    float4 v = ((const float4*)x)[i];
    u32 lo = (u32)f2bf(v.x) | ((u32)f2bf(v.y) << 16);
    u32 hi = (u32)f2bf(v.z) | ((u32)f2bf(v.w) << 16);
    uint2 o; o.x = lo; o.y = hi;
    ((uint2*)xb)[i] = o;
    return;
  }
  if (bid < 4608) {
    int tid = (bid - 4096) * 256 + threadIdx.x;   // SEQ*32
    int pos = tid >> 5, j = tid & 31;
    float theta = exp2f(-0.311430758895f * (float)j);  // 1000^(-j/32)
    float a = (float)pos * theta;
    float s, c;
    sincosf(a, &s, &c);
    cosT[tid] = c;
    sinT[tid] = s;
    return;
  }
  // weight transposes: dst[c][r] = bf16(src[r][c]) via padded LDS tile
  __shared__ float tile[64][65];
  int wb = bid - 4608;
  const float* src; u16* dst; int sstride, bx, by;
  if (wb < 256)      { src = Wq; dst = Wt;               sstride = 1024; bx = wb & 15;        by = wb >> 4; }
  else if (wb < 320) { src = Wk; dst = Wt + 1024 * 1024; sstride = 256;  bx = (wb - 256) & 3; by = (wb - 256) >> 2; }
  else if (wb < 384) { src = Wv; dst = Wt + 1280 * 1024; sstride = 256;  bx = (wb - 320) & 3; by = (wb - 320) >> 2; }
  else               { src = Wo; dst = Wto;              sstride = 1024; bx = (wb - 384) & 15; by = (wb - 384) >> 4; }
  const int dstride = 1024;
  int br = by * 64, bc = bx * 64;
  int t = threadIdx.x;
#pragma unroll
  for (int i = 0; i < 16; ++i) {
    int idx = t + i * 256;
    int r = idx >> 6, c = idx & 63;
    tile[r][c] = src[(long)(br + r) * sstride + bc + c];
  }
  __syncthreads();
#pragma unroll
  for (int i = 0; i < 16; ++i) {
    int idx = t + i * 256;
    int cc = idx >> 6, rr = idx & 63;
    dst[(long)(bc + cc) * dstride + br + rr] = f2bf(tile[rr][cc]);
  }
}

// ---------------- GEMM (standard): 128x64 tile, m97 structure (R12-proven) ------
__global__ __launch_bounds__(256) void k_gemm(const u16* __restrict__ A,
                                              const u16* __restrict__ Bt,
                                              float* __restrict__ C,
                                              int M, int N, int K) {
  __shared__ __align__(16) u16 a_lds[128 * 64];
  __shared__ __align__(16) u16 b_lds[64 * 64];
  const int bm = blockIdx.x * 128, bn = blockIdx.y * 64;
  const int t = threadIdx.x;
  const int l = t & 63, w = t >> 6;
  const int wm = (w >> 1) * 64, wn = (w & 1) * 32;
  const int lg = l >> 4, ll = l & 15;

  const f32x4 vzero = {0.f, 0.f, 0.f, 0.f};
  f32x4 acc[4][2];
#pragma unroll
  for (int i = 0; i < 4; ++i)
#pragma unroll
    for (int j = 0; j < 2; ++j) acc[i][j] = vzero;

  const u16* ga = A + (long)(bm + w * 32 + (l >> 3)) * K + (l & 7) * 8;
  const u16* gb = Bt + (long)(bn + w * 16 + (l >> 3)) * K + (l & 7) * 8;
  u16* la = a_lds + w * 32 * 64;
  u16* lb = b_lds + w * 16 * 64;
  const long rstep = (long)8 * K;

  for (int kt = 0; kt < K; kt += 64) {
    __syncthreads();
#pragma unroll
    for (int i = 0; i < 4; ++i) gload16(ga + i * rstep, la + i * 512);
#pragma unroll
    for (int i = 0; i < 2; ++i) gload16(gb + i * rstep, lb + i * 512);
    ga += 64; gb += 64;
    __syncthreads();
#pragma unroll
    for (int kc = 0; kc < 2; ++kc) {
      short8 af[4], bfr[2];
#pragma unroll
      for (int mi = 0; mi < 4; ++mi)
        af[mi] = *(const short8*)(a_lds + (wm + mi * 16 + ll) * 64 + kc * 32 + lg * 8);
#pragma unroll
      for (int nb = 0; nb < 2; ++nb)
        bfr[nb] = *(const short8*)(b_lds + (wn + nb * 16 + ll) * 64 + kc * 32 + lg * 8);
#pragma unroll
      for (int mi = 0; mi < 4; ++mi)
#pragma unroll
        for (int nb = 0; nb < 2; ++nb)
          acc[mi][nb] = __builtin_amdgcn_mfma_f32_16x16x32_bf16(af[mi], bfr[nb],
                                                                acc[mi][nb], 0, 0, 0);
    }
  }
  const int rbase = bm + wm + lg * 4;
  const int cbase = bn + wn + ll;
#pragma unroll
  for (int mi = 0; mi < 4; ++mi)
#pragma unroll
    for (int nb = 0; nb < 2; ++nb)
#pragma unroll
      for (int r = 0; r < 4; ++r)
        C[(long)(rbase + mi * 16 + r) * N + cbase + nb * 16] = acc[mi][nb][r];
}

// ---------------- fused QKV-GEMM (128x64, R12-proven): rope q/k + permuted-v ------
__global__ __launch_bounds__(256) void k_gemmqkv(const u16* __restrict__ A,
                                                 const u16* __restrict__ Bt,
                                                 const float* __restrict__ cosT,
                                                 const float* __restrict__ sinT,
                                                 u16* __restrict__ qb,
                                                 u16* __restrict__ kb,
                                                 u16* __restrict__ vb) {
  const int K = 1024;
  __shared__ __align__(16) u16 a_lds[128 * 64];
  __shared__ __align__(16) u16 b_lds[64 * 64];
  const int bm = blockIdx.x * 128, bn = blockIdx.y * 64;
  const int t = threadIdx.x;
  const int l = t & 63, w = t >> 6;
  const int wm = (w >> 1) * 64, wn = (w & 1) * 32;
  const int lg = l >> 4, ll = l & 15;

  const f32x4 vzero = {0.f, 0.f, 0.f, 0.f};
  f32x4 acc[4][2];
#pragma unroll
  for (int i = 0; i < 4; ++i)
#pragma unroll
    for (int j = 0; j < 2; ++j) acc[i][j] = vzero;

  const u16* ga = A + (long)(bm + w * 32 + (l >> 3)) * K + (l & 7) * 8;
  const u16* gb = Bt + (long)(bn + w * 16 + (l >> 3)) * K + (l & 7) * 8;
  u16* la = a_lds + w * 32 * 64;
  u16* lb = b_lds + w * 16 * 64;
  const long rstep = (long)8 * K;

  for (int kt = 0; kt < K; kt += 64) {
    __syncthreads();
#pragma unroll
    for (int i = 0; i < 4; ++i) gload16(ga + i * rstep, la + i * 512);
#pragma unroll
    for (int i = 0; i < 2; ++i) gload16(gb + i * rstep, lb + i * 512);
    ga += 64; gb += 64;
    __syncthreads();
#pragma unroll
    for (int kc = 0; kc < 2; ++kc) {
      short8 af[4], bfr[2];
#pragma unroll
      for (int mi = 0; mi < 4; ++mi)
        af[mi] = *(const short8*)(a_lds + (wm + mi * 16 + ll) * 64 + kc * 32 + lg * 8);
#pragma unroll
      for (int nb = 0; nb < 2; ++nb)
        bfr[nb] = *(const short8*)(b_lds + (wn + nb * 16 + ll) * 64 + kc * 32 + lg * 8);
#pragma unroll
      for (int mi = 0; mi < 4; ++mi)
#pragma unroll
        for (int nb = 0; nb < 2; ++nb)
          acc[mi][nb] = __builtin_amdgcn_mfma_f32_16x16x32_bf16(af[mi], bfr[nb],
                                                                acc[mi][nb], 0, 0, 0);
    }
  }

  const int rbase = bm + wm + lg * 4;
  const int cbase = bn + wn + ll;
  const int by = blockIdx.y;

  if (by < 20) {
    // q or k columns: rope. partner col = col^1 lives in lane ll^1.
    const float scale = (by < 16) ? 0.18033688011112042f : 1.0f;  // q: 0.125*log2e
#pragma unroll
    for (int mi = 0; mi < 4; ++mi)
#pragma unroll
      for (int nb = 0; nb < 2; ++nb) {
        int col = cbase + nb * 16;
        int j = (col & 63) >> 1;
        long hb = (by < 16) ? (long)(col >> 6) * SEQ
                            : (long)((col - 1024) >> 6) * SEQ;
        u16* dst0 = ((by < 16) ? qb : kb) + hb * 64 + (col & 63);
#pragma unroll
        for (int r = 0; r < 4; ++r) {
          float v0 = acc[mi][nb][r];
          float vp = __shfl_xor(v0, 1);
          int row = rbase + mi * 16 + r;
          float c = cosT[(row << 5) + j], s = sinT[(row << 5) + j];
          float res = (ll & 1) ? (vp * s + v0 * c) * scale
                               : (v0 * c - vp * s) * scale;
          dst0[(long)row * 64] = f2bf(res);
        }
      }
  } else {
    // v columns: write transposed + per-64-tile slot-permuted vT'[kv][d][seq]
#pragma unroll
    for (int mi = 0; mi < 4; ++mi)
#pragma unroll
      for (int nb = 0; nb < 2; ++nb) {
        int col = cbase + nb * 16;       // 1280..1535
        int vd = col - 1280;             // kv*64 + d
        int row0 = rbase + mi * 16;      // 4 consecutive keys, row0 % 4 == 0
        int T = row0 & ~63;              // tile base
        int kb64 = row0 & 63;
        int s0 = (kb64 & 32) + ((kb64 & 12) << 1) + ((kb64 & 16) >> 2);
        uint2 gg;
        gg.x = pk2(acc[mi][nb][0], acc[mi][nb][1]);
        gg.y = pk2(acc[mi][nb][2], acc[mi][nb][3]);
        *(uint2*)(vb + (long)vd * SEQ + T + s0) = gg;
      }
  }
}

// ---------------- Flash attention: 2x2 wave split, K direct-from-L2 ----------------
// 1024 blocks x 256 threads, LPT. Wave (wq,wk): q-rows [wq*32,+32), keys [wk*32,+32).
// K fragments loaded straight from global into REGISTERS (L2-resident, rows are
// 128B-contiguous so line inflation is only 2x) -> no K LDS, no K barrier dep.
// V stays staged (dbuf, 16 KB total) -> LDS ~16.3 KB doubles potential residency.
// No max tracking; ones-MFMA rowsum; P in-register (permuted V).
__global__ __launch_bounds__(256) void k_attn(const u16* __restrict__ q,
                                              const u16* __restrict__ kk,
                                              const u16* __restrict__ vT,
                                              u16* __restrict__ o) {
  const int b = blockIdx.x;
  const int h = b & 15;
  const int qt = 63 - (b >> 4);          // LPT: biggest blocks dispatched first
  const int hkv = h >> 2;
  __shared__ __align__(16) u16 vbuf[2][64 * 64];   // 16 KB total (dbuf V)
  __shared__ float lsm1[64];                        // 256 B (combine scratch)
  const int t = threadIdx.x, w = t >> 6, l = t & 63;
  const int lg = l >> 4, ll = l & 15;
  const int wq = w >> 1, wk = w & 1;
  const f32x4 vzero = {0.f, 0.f, 0.f, 0.f};
  const short8 vones = {0x3F80, 0x3F80, 0x3F80, 0x3F80,
                        0x3F80, 0x3F80, 0x3F80, 0x3F80};   // bf16 1.0 x8

  // --- V staging: wave w stages d-rows [w*16,+16); LDS[row][cs]=data[row][cs^(row&7)]
  const int lr = l >> 3, lc = l & 7;
  const int cswz = lc ^ (lr & 7);
  const u16* vbase = vT + (long)hkv * 64 * SEQ;
  const u16* vcurA = vbase + (long)(w * 16 + lr) * SEQ + cswz * 8;  // += 64/tile
  const u16* vcurB = vcurA + (long)8 * SEQ;

  // --- K direct: lane (lg,ll) of wave wk-half reads K[row=wk*32+st*16+ll][c*32+lg*8]
  const u16* kptr = kk + (long)hkv * SEQ * 64 + (long)(wk * 32 + ll) * 64 + lg * 8;

  const int rbyte = ll * 128;
  const int gv = ((wk * 4 + lg) ^ (ll & 7)) << 4;   // wk-half V slot chunks

  short8 kf00, kf01, kf10, kf11;   // K frags for current tile (st x c)
#define LOADK(T)                                                             \
  {                                                                          \
    const u16* kp_ = kptr + (long)(T) * 4096;                                \
    kf00 = *(const short8*)(kp_);                                            \
    kf01 = *(const short8*)(kp_ + 32);                                       \
    kf10 = *(const short8*)(kp_ + 1024);                                     \
    kf11 = *(const short8*)(kp_ + 1056);                                     \
  }
#define ISSUE_V(BUF)                                                         \
  {                                                                          \
    u16* vld = vbuf[BUF] + w * 1024;                                         \
    gload16(vcurA, vld);         gload16(vcurB, vld + 512);                  \
    vcurA += 64; vcurB += 64;                                                \
  }

  LOADK(0);
  ISSUE_V(0);
  int buf = 0;

  const int q0 = qt * 64;
  short8 qa[2][2];
#pragma unroll
  for (int g = 0; g < 2; ++g)
#pragma unroll
    for (int c = 0; c < 2; ++c)
      qa[g][c] = *(const short8*)(q + ((long)(h * SEQ + q0 + wq * 32 + g * 16 + ll) * 64 +
                                       c * 32 + lg * 8));

  f32x4 Oacc[2][4];
#pragma unroll
  for (int g = 0; g < 2; ++g)
#pragma unroll
    for (int nb = 0; nb < 4; ++nb) Oacc[g][nb] = vzero;
  f32x4 lsum[2] = {vzero, vzero};

  for (int kt = 0; kt <= qt; ++kt) {
    VM_DRAIN();        // own V gloads (tile kt) + K loads drained (belt)
    __syncthreads();   // all waves' V(kt) visible; prior vbuf[buf^1] reads done
    if (kt < qt) { ISSUE_V(buf ^ 1); }

    // QK^T (swapped) from K registers: S[st][g], lane ll reg r =
    //   S[key=wk*32+st*16+lg*4+r][q=wq*32+g*16+ll]
    f32x4 S[2][2];
    __builtin_amdgcn_s_setprio(1);
#pragma unroll
    for (int g = 0; g < 2; ++g) {
      f32x4 z0 = __builtin_amdgcn_mfma_f32_16x16x32_bf16(kf00, qa[g][0], vzero, 0, 0, 0);
      S[0][g]  = __builtin_amdgcn_mfma_f32_16x16x32_bf16(kf01, qa[g][1], z0, 0, 0, 0);
      f32x4 z1 = __builtin_amdgcn_mfma_f32_16x16x32_bf16(kf10, qa[g][0], vzero, 0, 0, 0);
      S[1][g]  = __builtin_amdgcn_mfma_f32_16x16x32_bf16(kf11, qa[g][1], z1, 0, 0, 0);
    }
    __builtin_amdgcn_s_setprio(0);
    if (kt < qt) { LOADK(kt + 1); }   // K regs free; cover = softmax+PV (L2 ~250cy)

    if (kt == qt) {   // diagonal tile: causal mask (tile-relative)
#pragma unroll
      for (int st = 0; st < 2; ++st)
#pragma unroll
        for (int g = 0; g < 2; ++g)
#pragma unroll
          for (int r = 0; r < 4; ++r)
            if (wk * 32 + st * 16 + lg * 4 + r > wq * 32 + g * 16 + ll)
              S[st][g][r] = -__builtin_inff();
    }

    // V fragments for this wave's key half (from staged LDS)
    const char* vb_ = (const char*)vbuf[buf] + rbyte;
    short8 vv[4];
#pragma unroll
    for (int nb = 0; nb < 4; ++nb)
      vv[nb] = *(const short8*)(vb_ + nb * 2048 + gv);

    // per q-group: exp2 -> truncating pack -> rowsum-MFMA + PV-MFMAs (k=32)
#pragma unroll
    for (int g = 0; g < 2; ++g) {
      float p00 = EXP2(S[0][g][0]), p01 = EXP2(S[0][g][1]);
      float p02 = EXP2(S[0][g][2]), p03 = EXP2(S[0][g][3]);
      float p10 = EXP2(S[1][g][0]), p11 = EXP2(S[1][g][1]);
      float p12 = EXP2(S[1][g][2]), p13 = EXP2(S[1][g][3]);
      uint4 u;
      u.x = pk2t(p00, p01); u.y = pk2t(p02, p03);
      u.z = pk2t(p10, p11); u.w = pk2t(p12, p13);
      short8 pa = __builtin_bit_cast(short8, u);
      __builtin_amdgcn_s_setprio(1);
      lsum[g] = __builtin_amdgcn_mfma_f32_16x16x32_bf16(pa, vones, lsum[g], 0, 0, 0);
      Oacc[g][0] = __builtin_amdgcn_mfma_f32_16x16x32_bf16(pa, vv[0], Oacc[g][0], 0, 0, 0);
      Oacc[g][1] = __builtin_amdgcn_mfma_f32_16x16x32_bf16(pa, vv[1], Oacc[g][1], 0, 0, 0);
      Oacc[g][2] = __builtin_amdgcn_mfma_f32_16x16x32_bf16(pa, vv[2], Oacc[g][2], 0, 0, 0);
      Oacc[g][3] = __builtin_amdgcn_mfma_f32_16x16x32_bf16(pa, vv[3], Oacc[g][3], 0, 0, 0);
      __builtin_amdgcn_s_setprio(0);
    }
    buf ^= 1;
  }
#undef LOADK
#undef ISSUE_V

  // ---- combine wk partials: wk=1 spills to retired LDS; wk=0 adds from regs ----
  __syncthreads();                       // staging buffer retired
  float* O1f = (float*)vbuf;             // 64x64 f32 = exactly 16 KB
  if (wk) {
#pragma unroll
    for (int g = 0; g < 2; ++g) {
#pragma unroll
      for (int nb = 0; nb < 4; ++nb)
#pragma unroll
        for (int r = 0; r < 4; ++r)
          O1f[(wq * 32 + g * 16 + lg * 4 + r) * 64 + nb * 16 + ll] = Oacc[g][nb][r];
      if (ll == 0) {
#pragma unroll
        for (int r = 0; r < 4; ++r)
          lsm1[wq * 32 + g * 16 + lg * 4 + r] = lsum[g][r];
      }
    }
  }
  __syncthreads();
  if (!wk) {
#pragma unroll
    for (int g = 0; g < 2; ++g)
#pragma unroll
      for (int r = 0; r < 4; ++r) {
        int qr = wq * 32 + g * 16 + lg * 4 + r;
        float inv = 1.f / (lsum[g][r] + lsm1[qr]);
#pragma unroll
        for (int nb = 0; nb < 4; ++nb) {
          float v = Oacc[g][nb][r] + O1f[qr * 64 + nb * 16 + ll];
          o[(long)(q0 + qr) * 1024 + h * 64 + nb * 16 + ll] = f2bf(v * inv);
        }
      }
  }
}

extern "C" void kernel_launch(void* const* d_in, const int* in_sizes, int n_in,
                              void* d_out, int out_size, void* d_ws, size_t ws_size,
                              hipStream_t stream) {
  const float* x  = (const float*)d_in[0];
  // d_in[1] = mask (causal, implicit) — unused
  const float* Wq = (const float*)d_in[2];
  const float* Wk = (const float*)d_in[3];
  const float* Wv = (const float*)d_in[4];
  const float* Wo = (const float*)d_in[5];
  float* out = (float*)d_out;

  char* ws = (char*)d_ws;
  u16* xb    = (u16*)(ws + 25165824);               // 4096*1024*2    = 8388608 (x bf16 / attn_out)
  u16* Wt    = (u16*)(ws + 33554432);               // 1536*1024*2    = 3145728
  u16* Wto   = (u16*)(ws + 36700160);               // 1024*1024*2    = 2097152
  u16* qb    = (u16*)(ws + 38797312);               // 16*4096*64*2   = 8388608
  u16* kb    = (u16*)(ws + 47185920);               // 4*4096*64*2    = 2097152
  u16* vb    = (u16*)(ws + 49283072);               // 4*64*4096*2    = 2097152
  float* cosT = (float*)(ws + 51380224);            // 4096*32*4      = 524288
  float* sinT = (float*)(ws + 51904512);            // 524288 -> total 52428800

  // fused prep: x conversion + RoPE tables + all weight transposes (ONE launch)
  k_prep<<<5248, 256, 0, stream>>>(x, xb, cosT, sinT, Wq, Wk, Wv, Wo, Wt, Wto);

  // fused: qb/kb/vb written directly (rope + permuted-transpose in epilogue)
  k_gemmqkv<<<dim3(32, 24), 256, 0, stream>>>(xb, Wt, cosT, sinT, qb, kb, vb);

  k_attn<<<1024, 256, 0, stream>>>(qb, kb, vb, xb);   // attn_out -> xb

  // out = attn_out @ Wo
  k_gemm<<<dim3(32, 16), 256, 0, stream>>>(xb, Wto, out, 4096, 1024, 1024);
}

// Round 24
// 102.304 us; speedup vs baseline: 1.3638x; 1.3638x over previous
//
#include <hip/hip_runtime.h>
#include <hip/hip_bf16.h>

typedef __attribute__((ext_vector_type(8))) short short8;   // 8 bf16 (4 VGPRs)
typedef __attribute__((ext_vector_type(4))) float f32x4;
typedef unsigned short u16;
typedef unsigned int u32;

#define SEQ 4096

__device__ __forceinline__ u16 f2bf(float f) {
  return __builtin_bit_cast(u16, __float2bfloat16(f));
}

// exp2: builtin (compiler handles TRANS hazards) or libm fallback. NO raw asm.
#if __has_builtin(__builtin_amdgcn_exp2f)
#define EXP2(x) __builtin_amdgcn_exp2f(x)
#else
#define EXP2(x) exp2f(x)
#endif

// pack two f32 -> bf16x2 (round-half-up via +0x8000, then byte-perm the hi16s)
__device__ __forceinline__ u32 pk2(float a, float b) {
  u32 ua = __builtin_bit_cast(u32, a) + 0x8000u;
  u32 ub = __builtin_bit_cast(u32, b) + 0x8000u;
  return __builtin_amdgcn_perm(ub, ua, 0x07060302);  // {hi16(ub), hi16(ua)}
}

// pack two f32 -> bf16x2 TRUNCATING (1 op). Safe for P: the ones-MFMA row-sum
// is computed from the SAME truncated values, so the softmax ratio is unbiased.
__device__ __forceinline__ u32 pk2t(float a, float b) {
  return __builtin_amdgcn_perm(__builtin_bit_cast(u32, b),
                               __builtin_bit_cast(u32, a), 0x07060302);
}

// global -> LDS direct (16B/lane). LDS dest = wave-uniform base + lane*16.
typedef __attribute__((address_space(1))) u32 gas_u32;
typedef __attribute__((address_space(3))) u32 las_u32;
__device__ __forceinline__ void gload16(const u16* g, const u16* l) {
  __builtin_amdgcn_global_load_lds((gas_u32*)(unsigned long long)(const void*)g,
                                   (las_u32*)(u32)(unsigned long long)(const void*)l,
                                   16, 0, 0);
}

// explicit own-wave vmem drain (belt for the barrier's implicit drain)
#define VM_DRAIN() asm volatile("s_waitcnt vmcnt(0)" ::: "memory")

// ---------------- fused prep (ONE launch): x->bf16, RoPE tables, W transposes -----
// blocks [0,4096): x fp32->bf16; [4096,4608): cos/sin tables;
// [4608,4864): Wq^T; [4864,4928): Wk^T; [4928,4992): Wv^T; [4992,5248): Wo^T.
__global__ __launch_bounds__(256) void k_prep(const float* __restrict__ x,
                                              u16* __restrict__ xb,
                                              float* __restrict__ cosT,
                                              float* __restrict__ sinT,
                                              const float* __restrict__ Wq,
                                              const float* __restrict__ Wk,
                                              const float* __restrict__ Wv,
                                              const float* __restrict__ Wo,
                                              u16* __restrict__ Wt,
                                              u16* __restrict__ Wto) {
  int bid = blockIdx.x;
  if (bid < 4096) {
    int i = bid * 256 + threadIdx.x;     // one float4 each
    float4 v = ((const float4*)x)[i];
    u32 lo = (u32)f2bf(v.x) | ((u32)f2bf(v.y) << 16);
    u32 hi = (u32)f2bf(v.z) | ((u32)f2bf(v.w) << 16);
    uint2 o; o.x = lo; o.y = hi;
    ((uint2*)xb)[i] = o;
    return;
  }
  if (bid < 4608) {
    int tid = (bid - 4096) * 256 + threadIdx.x;   // SEQ*32
    int pos = tid >> 5, j = tid & 31;
    float theta = exp2f(-0.311430758895f * (float)j);  // 1000^(-j/32)
    float a = (float)pos * theta;
    float s, c;
    sincosf(a, &s, &c);
    cosT[tid] = c;
    sinT[tid] = s;
    return;
  }
  // weight transposes: dst[c][r] = bf16(src[r][c]) via padded LDS tile
  __shared__ float tile[64][65];
  int wb = bid - 4608;
  const float* src; u16* dst; int sstride, bx, by;
  if (wb < 256)      { src = Wq; dst = Wt;               sstride = 1024; bx = wb & 15;        by = wb >> 4; }
  else if (wb < 320) { src = Wk; dst = Wt + 1024 * 1024; sstride = 256;  bx = (wb - 256) & 3; by = (wb - 256) >> 2; }
  else if (wb < 384) { src = Wv; dst = Wt + 1280 * 1024; sstride = 256;  bx = (wb - 320) & 3; by = (wb - 320) >> 2; }
  else               { src = Wo; dst = Wto;              sstride = 1024; bx = (wb - 384) & 15; by = (wb - 384) >> 4; }
  const int dstride = 1024;
  int br = by * 64, bc = bx * 64;
  int t = threadIdx.x;
#pragma unroll
  for (int i = 0; i < 16; ++i) {
    int idx = t + i * 256;
    int r = idx >> 6, c = idx & 63;
    tile[r][c] = src[(long)(br + r) * sstride + bc + c];
  }
  __syncthreads();
#pragma unroll
  for (int i = 0; i < 16; ++i) {
    int idx = t + i * 256;
    int cc = idx >> 6, rr = idx & 63;
    dst[(long)(bc + cc) * dstride + br + rr] = f2bf(tile[rr][cc]);
  }
}

// ---------------- GEMM (standard): 128x64 tile, m97 structure (R12-proven) ------
__global__ __launch_bounds__(256) void k_gemm(const u16* __restrict__ A,
                                              const u16* __restrict__ Bt,
                                              float* __restrict__ C,
                                              int M, int N, int K) {
  __shared__ __align__(16) u16 a_lds[128 * 64];
  __shared__ __align__(16) u16 b_lds[64 * 64];
  const int bm = blockIdx.x * 128, bn = blockIdx.y * 64;
  const int t = threadIdx.x;
  const int l = t & 63, w = t >> 6;
  const int wm = (w >> 1) * 64, wn = (w & 1) * 32;
  const int lg = l >> 4, ll = l & 15;

  const f32x4 vzero = {0.f, 0.f, 0.f, 0.f};
  f32x4 acc[4][2];
#pragma unroll
  for (int i = 0; i < 4; ++i)
#pragma unroll
    for (int j = 0; j < 2; ++j) acc[i][j] = vzero;

  const u16* ga = A + (long)(bm + w * 32 + (l >> 3)) * K + (l & 7) * 8;
  const u16* gb = Bt + (long)(bn + w * 16 + (l >> 3)) * K + (l & 7) * 8;
  u16* la = a_lds + w * 32 * 64;
  u16* lb = b_lds + w * 16 * 64;
  const long rstep = (long)8 * K;

  for (int kt = 0; kt < K; kt += 64) {
    __syncthreads();
#pragma unroll
    for (int i = 0; i < 4; ++i) gload16(ga + i * rstep, la + i * 512);
#pragma unroll
    for (int i = 0; i < 2; ++i) gload16(gb + i * rstep, lb + i * 512);
    ga += 64; gb += 64;
    __syncthreads();
#pragma unroll
    for (int kc = 0; kc < 2; ++kc) {
      short8 af[4], bfr[2];
#pragma unroll
      for (int mi = 0; mi < 4; ++mi)
        af[mi] = *(const short8*)(a_lds + (wm + mi * 16 + ll) * 64 + kc * 32 + lg * 8);
#pragma unroll
      for (int nb = 0; nb < 2; ++nb)
        bfr[nb] = *(const short8*)(b_lds + (wn + nb * 16 + ll) * 64 + kc * 32 + lg * 8);
#pragma unroll
      for (int mi = 0; mi < 4; ++mi)
#pragma unroll
        for (int nb = 0; nb < 2; ++nb)
          acc[mi][nb] = __builtin_amdgcn_mfma_f32_16x16x32_bf16(af[mi], bfr[nb],
                                                                acc[mi][nb], 0, 0, 0);
    }
  }
  const int rbase = bm + wm + lg * 4;
  const int cbase = bn + wn + ll;
#pragma unroll
  for (int mi = 0; mi < 4; ++mi)
#pragma unroll
    for (int nb = 0; nb < 2; ++nb)
#pragma unroll
      for (int r = 0; r < 4; ++r)
        C[(long)(rbase + mi * 16 + r) * N + cbase + nb * 16] = acc[mi][nb][r];
}

// ---------------- fused QKV-GEMM (128x64, R12-proven): rope q/k + permuted-v ------
__global__ __launch_bounds__(256) void k_gemmqkv(const u16* __restrict__ A,
                                                 const u16* __restrict__ Bt,
                                                 const float* __restrict__ cosT,
                                                 const float* __restrict__ sinT,
                                                 u16* __restrict__ qb,
                                                 u16* __restrict__ kb,
                                                 u16* __restrict__ vb) {
  const int K = 1024;
  __shared__ __align__(16) u16 a_lds[128 * 64];
  __shared__ __align__(16) u16 b_lds[64 * 64];
  const int bm = blockIdx.x * 128, bn = blockIdx.y * 64;
  const int t = threadIdx.x;
  const int l = t & 63, w = t >> 6;
  const int wm = (w >> 1) * 64, wn = (w & 1) * 32;
  const int lg = l >> 4, ll = l & 15;

  const f32x4 vzero = {0.f, 0.f, 0.f, 0.f};
  f32x4 acc[4][2];
#pragma unroll
  for (int i = 0; i < 4; ++i)
#pragma unroll
    for (int j = 0; j < 2; ++j) acc[i][j] = vzero;

  const u16* ga = A + (long)(bm + w * 32 + (l >> 3)) * K + (l & 7) * 8;
  const u16* gb = Bt + (long)(bn + w * 16 + (l >> 3)) * K + (l & 7) * 8;
  u16* la = a_lds + w * 32 * 64;
  u16* lb = b_lds + w * 16 * 64;
  const long rstep = (long)8 * K;

  for (int kt = 0; kt < K; kt += 64) {
    __syncthreads();
#pragma unroll
    for (int i = 0; i < 4; ++i) gload16(ga + i * rstep, la + i * 512);
#pragma unroll
    for (int i = 0; i < 2; ++i) gload16(gb + i * rstep, lb + i * 512);
    ga += 64; gb += 64;
    __syncthreads();
#pragma unroll
    for (int kc = 0; kc < 2; ++kc) {
      short8 af[4], bfr[2];
#pragma unroll
      for (int mi = 0; mi < 4; ++mi)
        af[mi] = *(const short8*)(a_lds + (wm + mi * 16 + ll) * 64 + kc * 32 + lg * 8);
#pragma unroll
      for (int nb = 0; nb < 2; ++nb)
        bfr[nb] = *(const short8*)(b_lds + (wn + nb * 16 + ll) * 64 + kc * 32 + lg * 8);
#pragma unroll
      for (int mi = 0; mi < 4; ++mi)
#pragma unroll
        for (int nb = 0; nb < 2; ++nb)
          acc[mi][nb] = __builtin_amdgcn_mfma_f32_16x16x32_bf16(af[mi], bfr[nb],
                                                                acc[mi][nb], 0, 0, 0);
    }
  }

  const int rbase = bm + wm + lg * 4;
  const int cbase = bn + wn + ll;
  const int by = blockIdx.y;

  if (by < 20) {
    // q or k columns: rope. partner col = col^1 lives in lane ll^1.
    const float scale = (by < 16) ? 0.18033688011112042f : 1.0f;  // q: 0.125*log2e
#pragma unroll
    for (int mi = 0; mi < 4; ++mi)
#pragma unroll
      for (int nb = 0; nb < 2; ++nb) {
        int col = cbase + nb * 16;
        int j = (col & 63) >> 1;
        long hb = (by < 16) ? (long)(col >> 6) * SEQ
                            : (long)((col - 1024) >> 6) * SEQ;
        u16* dst0 = ((by < 16) ? qb : kb) + hb * 64 + (col & 63);
#pragma unroll
        for (int r = 0; r < 4; ++r) {
          float v0 = acc[mi][nb][r];
          float vp = __shfl_xor(v0, 1);
          int row = rbase + mi * 16 + r;
          float c = cosT[(row << 5) + j], s = sinT[(row << 5) + j];
          float res = (ll & 1) ? (vp * s + v0 * c) * scale
                               : (v0 * c - vp * s) * scale;
          dst0[(long)row * 64] = f2bf(res);
        }
      }
  } else {
    // v columns: write transposed + per-64-tile slot-permuted vT'[kv][d][seq]
#pragma unroll
    for (int mi = 0; mi < 4; ++mi)
#pragma unroll
      for (int nb = 0; nb < 2; ++nb) {
        int col = cbase + nb * 16;       // 1280..1535
        int vd = col - 1280;             // kv*64 + d
        int row0 = rbase + mi * 16;      // 4 consecutive keys, row0 % 4 == 0
        int T = row0 & ~63;              // tile base
        int kb64 = row0 & 63;
        int s0 = (kb64 & 32) + ((kb64 & 12) << 1) + ((kb64 & 16) >> 2);
        uint2 gg;
        gg.x = pk2(acc[mi][nb][0], acc[mi][nb][1]);
        gg.y = pk2(acc[mi][nb][2], acc[mi][nb][3]);
        *(uint2*)(vb + (long)vd * SEQ + T + s0) = gg;
      }
  }
}

// ---------------- Flash attention: 2x2 wave split (32q x 32k per wave) ------------
// 1024 blocks x 256 threads, LPT. Wave (wq,wk): q-rows [wq*32,+32), keys [wk*32,+32).
// LDS exactly 32 KB: wk=0 waves keep O0/l0 in REGISTERS; wk=1 spill O1/l1 into
// retired staging LDS. No max tracking; ones-MFMA rowsum; P in-register (permuted V).
__global__ __launch_bounds__(256) void k_attn(const u16* __restrict__ q,
                                              const u16* __restrict__ kk,
                                              const u16* __restrict__ vT,
                                              u16* __restrict__ o) {
  const int b = blockIdx.x;
  const int h = b & 15;
  const int qt = 63 - (b >> 4);          // LPT: biggest blocks dispatched first
  const int hkv = h >> 2;
  __shared__ __align__(16) u16 kbuf[2][64 * 64];   // 16 KB
  __shared__ __align__(16) u16 vbuf[2][64 * 64];   // 16 KB  (total = 32768 exactly)
  const int t = threadIdx.x, w = t >> 6, l = t & 63;
  const int lg = l >> 4, ll = l & 15;
  const int wq = w >> 1, wk = w & 1;
  const f32x4 vzero = {0.f, 0.f, 0.f, 0.f};
  const short8 vones = {0x3F80, 0x3F80, 0x3F80, 0x3F80,
                        0x3F80, 0x3F80, 0x3F80, 0x3F80};   // bf16 1.0 x8

  // --- staging: wave w stages rows [w*16,+16) of K and of V(d) ---
  const int lr = l >> 3, lc = l & 7;
  const int cswz = lc ^ (lr & 7);
  const u16* kbase = kk + (long)hkv * SEQ * 64;
  const u16* vbase = vT + (long)hkv * 64 * SEQ;
  const u16* kcur  = kbase + (long)(w * 16 + lr) * 64 + cswz * 8;   // += 4096/tile
  const u16* vcurA = vbase + (long)(w * 16 + lr) * SEQ + cswz * 8;  // += 64/tile
  const u16* vcurB = vcurA + (long)8 * SEQ;

  const int rbyte = ll * 128;
  const int g0 = (lg ^ (ll & 7)) << 4;
  const int g1 = ((lg ^ (ll & 7)) ^ 4) << 4;
  const int gv = ((wk * 4 + lg) ^ (ll & 7)) << 4;   // wk-half V slot chunks
  const int kwbyte = wk * 32 * 128;                 // wk-half key-row base (bytes)

#define ISSUE(BUF)                                                           \
  {                                                                          \
    u16* kld = kbuf[BUF] + w * 1024;                                         \
    u16* vld = vbuf[BUF] + w * 1024;                                         \
    gload16(kcur, kld);          gload16(kcur + 512, kld + 512);             \
    gload16(vcurA, vld);         gload16(vcurB, vld + 512);                  \
    kcur += 4096; vcurA += 64; vcurB += 64;                                  \
  }

  ISSUE(0);
  int buf = 0;

  const int q0 = qt * 64;
  short8 qa[2][2];
#pragma unroll
  for (int g = 0; g < 2; ++g)
#pragma unroll
    for (int c = 0; c < 2; ++c)
      qa[g][c] = *(const short8*)(q + ((long)(h * SEQ + q0 + wq * 32 + g * 16 + ll) * 64 +
                                       c * 32 + lg * 8));

  f32x4 Oacc[2][4];
#pragma unroll
  for (int g = 0; g < 2; ++g)
#pragma unroll
    for (int nb = 0; nb < 4; ++nb) Oacc[g][nb] = vzero;
  f32x4 lsum[2] = {vzero, vzero};

  for (int kt = 0; kt <= qt; ++kt) {
    VM_DRAIN();        // own gloads (tile kt) drained before barrier (belt)
    __syncthreads();   // all waves' tile-kt loads visible; prior buf^1 reads done
    if (kt < qt) { ISSUE(buf ^ 1); }

    const char* kb_ = (const char*)kbuf[buf] + kwbyte + rbyte;
    const char* vb_ = (const char*)vbuf[buf] + rbyte;

    // QK^T (swapped): S[st][g], lane ll reg r = S[key=wk*32+st*16+lg*4+r][q=wq*32+g*16+ll]
    f32x4 S[2][2];
    __builtin_amdgcn_s_setprio(1);
#pragma unroll
    for (int st = 0; st < 2; ++st) {
      short8 ka0 = *(const short8*)(kb_ + st * 2048 + g0);
      short8 ka1 = *(const short8*)(kb_ + st * 2048 + g1);
#pragma unroll
      for (int g = 0; g < 2; ++g) {
        f32x4 z = __builtin_amdgcn_mfma_f32_16x16x32_bf16(ka0, qa[g][0], vzero, 0, 0, 0);
        S[st][g] = __builtin_amdgcn_mfma_f32_16x16x32_bf16(ka1, qa[g][1], z, 0, 0, 0);
      }
    }
    __builtin_amdgcn_s_setprio(0);

    if (kt == qt) {   // diagonal tile: causal mask (tile-relative)
#pragma unroll
      for (int st = 0; st < 2; ++st)
#pragma unroll
        for (int g = 0; g < 2; ++g)
#pragma unroll
          for (int r = 0; r < 4; ++r)
            if (wk * 32 + st * 16 + lg * 4 + r > wq * 32 + g * 16 + ll)
              S[st][g][r] = -__builtin_inff();
    }

    // V fragments for this wave's key half
    short8 vv[4];
#pragma unroll
    for (int nb = 0; nb < 4; ++nb)
      vv[nb] = *(const short8*)(vb_ + nb * 2048 + gv);

    // per q-group: exp2 -> truncating pack -> rowsum-MFMA + PV-MFMAs (k=32)
#pragma unroll
    for (int g = 0; g < 2; ++g) {
      float p00 = EXP2(S[0][g][0]), p01 = EXP2(S[0][g][1]);
      float p02 = EXP2(S[0][g][2]), p03 = EXP2(S[0][g][3]);
      float p10 = EXP2(S[1][g][0]), p11 = EXP2(S[1][g][1]);
      float p12 = EXP2(S[1][g][2]), p13 = EXP2(S[1][g][3]);
      uint4 u;
      u.x = pk2t(p00, p01); u.y = pk2t(p02, p03);
      u.z = pk2t(p10, p11); u.w = pk2t(p12, p13);
      short8 pa = __builtin_bit_cast(short8, u);
      __builtin_amdgcn_s_setprio(1);
      lsum[g] = __builtin_amdgcn_mfma_f32_16x16x32_bf16(pa, vones, lsum[g], 0, 0, 0);
      Oacc[g][0] = __builtin_amdgcn_mfma_f32_16x16x32_bf16(pa, vv[0], Oacc[g][0], 0, 0, 0);
      Oacc[g][1] = __builtin_amdgcn_mfma_f32_16x16x32_bf16(pa, vv[1], Oacc[g][1], 0, 0, 0);
      Oacc[g][2] = __builtin_amdgcn_mfma_f32_16x16x32_bf16(pa, vv[2], Oacc[g][2], 0, 0, 0);
      Oacc[g][3] = __builtin_amdgcn_mfma_f32_16x16x32_bf16(pa, vv[3], Oacc[g][3], 0, 0, 0);
      __builtin_amdgcn_s_setprio(0);
    }
    buf ^= 1;
  }
#undef ISSUE

  // ---- combine wk partials: wk=1 spills to retired LDS; wk=0 adds from regs ----
  __syncthreads();                       // staging buffers retired
  float* O1f  = (float*)vbuf;            // 64x64 f32 = exactly 16 KB
  float* lsm1 = (float*)kbuf;            // 64 f32 (overlay on retired kbuf)
  if (wk) {
#pragma unroll
    for (int g = 0; g < 2; ++g) {
#pragma unroll
      for (int nb = 0; nb < 4; ++nb)
#pragma unroll
        for (int r = 0; r < 4; ++r)
          O1f[(wq * 32 + g * 16 + lg * 4 + r) * 64 + nb * 16 + ll] = Oacc[g][nb][r];
      if (ll == 0) {
#pragma unroll
        for (int r = 0; r < 4; ++r)
          lsm1[wq * 32 + g * 16 + lg * 4 + r] = lsum[g][r];
      }
    }
  }
  __syncthreads();
  if (!wk) {
#pragma unroll
    for (int g = 0; g < 2; ++g)
#pragma unroll
      for (int r = 0; r < 4; ++r) {
        int qr = wq * 32 + g * 16 + lg * 4 + r;
        float inv = 1.f / (lsum[g][r] + lsm1[qr]);
#pragma unroll
        for (int nb = 0; nb < 4; ++nb) {
          float v = Oacc[g][nb][r] + O1f[qr * 64 + nb * 16 + ll];
          o[(long)(q0 + qr) * 1024 + h * 64 + nb * 16 + ll] = f2bf(v * inv);
        }
      }
  }
}

extern "C" void kernel_launch(void* const* d_in, const int* in_sizes, int n_in,
                              void* d_out, int out_size, void* d_ws, size_t ws_size,
                              hipStream_t stream) {
  const float* x  = (const float*)d_in[0];
  // d_in[1] = mask (causal, implicit) — unused
  const float* Wq = (const float*)d_in[2];
  const float* Wk = (const float*)d_in[3];
  const float* Wv = (const float*)d_in[4];
  const float* Wo = (const float*)d_in[5];
  float* out = (float*)d_out;

  char* ws = (char*)d_ws;
  u16* xb    = (u16*)(ws + 25165824);               // 4096*1024*2    = 8388608 (x bf16 / attn_out)
  u16* Wt    = (u16*)(ws + 33554432);               // 1536*1024*2    = 3145728
  u16* Wto   = (u16*)(ws + 36700160);               // 1024*1024*2    = 2097152
  u16* qb    = (u16*)(ws + 38797312);               // 16*4096*64*2   = 8388608
  u16* kb    = (u16*)(ws + 47185920);               // 4*4096*64*2    = 2097152
  u16* vb    = (u16*)(ws + 49283072);               // 4*64*4096*2    = 2097152
  float* cosT = (float*)(ws + 51380224);            // 4096*32*4      = 524288
  float* sinT = (float*)(ws + 51904512);            // 524288 -> total 52428800

  // fused prep: x conversion + RoPE tables + all weight transposes (ONE launch)
  k_prep<<<5248, 256, 0, stream>>>(x, xb, cosT, sinT, Wq, Wk, Wv, Wo, Wt, Wto);

  // fused: qb/kb/vb written directly (rope + permuted-transpose in epilogue)
  k_gemmqkv<<<dim3(32, 24), 256, 0, stream>>>(xb, Wt, cosT, sinT, qb, kb, vb);

  k_attn<<<1024, 256, 0, stream>>>(qb, kb, vb, xb);   // attn_out -> xb

  // out = attn_out @ Wo
  k_gemm<<<dim3(32, 16), 256, 0, stream>>>(xb, Wto, out, 4096, 1024, 1024);
}